// Round 5
// baseline (839.269 us; speedup 1.0000x reference)
//
#include <hip/hip_runtime.h>
#include <hip/hip_bf16.h>

typedef __hip_bfloat16 bf16h;

__device__ __forceinline__ float bfu2f(unsigned short u) {
    return __uint_as_float(((unsigned int)u) << 16);
}

// ---------------- dtype detectors ----------------
// edge_index: int64 little-endian with values < 50000 => every odd int32 word 0.
__global__ void k_detect_e(const int* __restrict__ ei, int* __restrict__ flag) {
    int lane = threadIdx.x;  // 64 threads
    int v = ei[2 * lane + 1];
    unsigned long long b = __ballot(v == 0);
    if (lane == 0) *flag = (b == ~0ull) ? 1 : 0;
}

// x: packed bf16 pairs -> low 16 bits of each word are a bf16 ~N(0,1): exponent
// field in [0x76,0x82] ~99.8%/lane. fp32 -> those bits are mantissa noise (~5%).
__global__ void k_detect_x(const unsigned int* __restrict__ x, int* __restrict__ flag) {
    int lane = threadIdx.x;  // 64 threads
    unsigned int w = x[lane];
    unsigned int ef = (w >> 7) & 0xFFu;
    unsigned long long b = __ballot(ef >= 0x76u && ef <= 0x82u);
    if (lane == 0) *flag = (__popcll(b) >= 40) ? 1 : 0;
}

__global__ void k_zero(int* __restrict__ p, int n) {
    int i = blockIdx.x * 256 + threadIdx.x;
    if (i < n) p[i] = 0;
}

// convert W1/W2/b1/b2 to fp32 scratch, honoring detected dtype
__global__ void k_convW(const void* __restrict__ W1, const void* __restrict__ b1,
                        const void* __restrict__ W2, const void* __restrict__ b2,
                        const int* __restrict__ xf,
                        float* __restrict__ Wf1, float* __restrict__ bf1,
                        float* __restrict__ Wf2, float* __restrict__ bf2) {
    int i = blockIdx.x * 256 + threadIdx.x;
    bool isb = (*xf != 0);
    if (i < 16384) {
        Wf1[i] = isb ? bfu2f(((const unsigned short*)W1)[i]) : ((const float*)W1)[i];
        Wf2[i] = isb ? bfu2f(((const unsigned short*)W2)[i]) : ((const float*)W2)[i];
    }
    if (i < 128) {
        bf1[i] = isb ? bfu2f(((const unsigned short*)b1)[i]) : ((const float*)b1)[i];
        bf2[i] = isb ? bfu2f(((const unsigned short*)b2)[i]) : ((const float*)b2)[i];
    }
}

// ---------------- CSR build ----------------

__global__ void k_count(const int* __restrict__ ei, const int* __restrict__ flag,
                        int* __restrict__ cnt, int e, int n) {
    int i = blockIdx.x * 256 + threadIdx.x;
    if (i >= e) return;
    int st = (*flag) ? 2 : 1;
    int d = ei[(size_t)e * st + (size_t)i * st];
    if (d >= 0 && d < n) atomicAdd(&cnt[d], 1);
}

__global__ void k_dinv(const int* __restrict__ cnt, float* __restrict__ dinv, int n) {
    int i = blockIdx.x * 256 + threadIdx.x;
    if (i < n) dinv[i] = rsqrtf(fmaxf((float)cnt[i], 0.f) + 1.0f);
}

__global__ void k_scan64(const int* __restrict__ cnt, int* __restrict__ off,
                         int* __restrict__ cur, int n) {
    int lane = threadIdx.x;  // 64 threads
    int carry = 0;
    for (int base = 0; base <= n; base += 64) {
        int i = base + lane;
        int v = (i < n) ? cnt[i] : 0;
        int incl = v;
#pragma unroll
        for (int d = 1; d < 64; d <<= 1) {
            int u = __shfl_up(incl, d, 64);
            if (lane >= d) incl += u;
        }
        if (i <= n) {
            int excl = carry + incl - v;
            off[i] = excl;
            if (i < n) cur[i] = excl;
        }
        carry += __shfl(incl, 63, 64);
    }
}

__global__ void k_fill(const int* __restrict__ ei, const int* __restrict__ flag,
                       const float* __restrict__ dinv, int* __restrict__ cur,
                       int* __restrict__ csrc, float* __restrict__ cnorm, int e, int n) {
    int i = blockIdx.x * 256 + threadIdx.x;
    if (i >= e) return;
    int st = (*flag) ? 2 : 1;
    int s = ei[(size_t)i * st];
    int d = ei[(size_t)e * st + (size_t)i * st];
    if (s < 0 || s >= n || d < 0 || d >= n) return;
    int pos = atomicAdd(&cur[d], 1);
    csrc[pos] = s;
    cnorm[pos] = dinv[s] * dinv[d];
}

// ---------------- Aggregate (linear): B[v] = sum norm*X[src] + dinv^2*X[v] ----
// One wave/node, 2 elems/lane, fp32 accumulate, bf16x2 store to B.
// mode: 0 = use *xflag (layer-1 input), 1 = force fp32 (layer-2, reads d_out fp32)
__global__ __launch_bounds__(256) void k_agg(const void* __restrict__ X,
                                             const int* __restrict__ xflag, int force_f32,
                                             const int* __restrict__ off,
                                             const int* __restrict__ csrc,
                                             const float* __restrict__ cnorm,
                                             const float* __restrict__ dinv,
                                             __hip_bfloat162* __restrict__ outb, int n) {
    int node = blockIdx.x * 4 + (threadIdx.x >> 6);
    if (node >= n) return;
    int lane = threadIdx.x & 63;
    bool isb = (!force_f32) && (*xflag != 0);
    int beg = off[node], end = off[node + 1];
    float ax = 0.f, ay = 0.f;
    if (isb) {
        const unsigned int* Xb = (const unsigned int*)X;  // packed bf16 pair
        for (int j = beg; j < end; ++j) {
            int s = csrc[j];
            if ((unsigned)s >= (unsigned)n) continue;
            float w = cnorm[j];
            unsigned int v = Xb[(size_t)s * 64 + lane];
            ax += w * bfu2f((unsigned short)(v & 0xffffu));
            ay += w * bfu2f((unsigned short)(v >> 16));
        }
        float wd = dinv[node]; wd *= wd;
        unsigned int v = Xb[(size_t)node * 64 + lane];
        ax += wd * bfu2f((unsigned short)(v & 0xffffu));
        ay += wd * bfu2f((unsigned short)(v >> 16));
    } else {
        const float2* Xf = (const float2*)X;
        for (int j = beg; j < end; ++j) {
            int s = csrc[j];
            if ((unsigned)s >= (unsigned)n) continue;
            float w = cnorm[j];
            float2 v = Xf[(size_t)s * 64 + lane];
            ax += w * v.x;
            ay += w * v.y;
        }
        float wd = dinv[node]; wd *= wd;
        float2 v = Xf[(size_t)node * 64 + lane];
        ax += wd * v.x;
        ay += wd * v.y;
    }
    __hip_bfloat162 o;
    o.x = __float2bfloat16(ax);
    o.y = __float2bfloat16(ay);
    outb[(size_t)node * 64 + lane] = o;
}

// ---------------- Fused GEMM: Out_f32 = relu(A_bf16 @ W_f32 + b) ----
// 256 thr, 48 rows/block; thread tile 6 rows x 4 cols; two 64-col passes.
// sA 24 KB fp32 (wave-broadcast), sW 32 KB fp32 verbatim chunk. Output fp32!
__global__ __launch_bounds__(256) void k_gemm_fused(const unsigned short* __restrict__ A,
                                                    const float* __restrict__ W,
                                                    const float* __restrict__ bias,
                                                    float* __restrict__ Out, int n) {
    __shared__ float sA[48 * 128];
    __shared__ float sW[128 * 64];
    int t = threadIdx.x;
    int rowBase = blockIdx.x * 48;

#pragma unroll
    for (int i = 0; i < 6; ++i) {  // stage A tile bf16 -> fp32
        int idx4 = (t + i * 256) * 4;
        int r = idx4 >> 7, cc = idx4 & 127;
        int grow = rowBase + r;
        float4 f = make_float4(0.f, 0.f, 0.f, 0.f);
        if (grow < n) {
            ushort4 u = *(const ushort4*)(A + (size_t)grow * 128 + cc);
            f.x = bfu2f(u.x); f.y = bfu2f(u.y); f.z = bfu2f(u.z); f.w = bfu2f(u.w);
        }
        *(float4*)(sA + r * 128 + cc) = f;
    }

    int tc = t & 31, tr = t >> 5;
    int row0 = tr * 6;
    float acc[4][6];

    for (int p = 0; p < 2; ++p) {
        __syncthreads();
#pragma unroll
        for (int i = 0; i < 8; ++i) {  // stage W cols [64p,64p+64) verbatim
            int idx4 = (t + i * 256) * 4;
            int k = idx4 >> 6, cc = idx4 & 63;
            *(float4*)(sW + k * 64 + cc) = *(const float4*)(W + k * 128 + 64 * p + cc);
        }
        __syncthreads();

        float a0[6] = {}, a1[6] = {};
        for (int kk = 0; kk < 128; kk += 4) {
            float w0[4], w1[4];
#pragma unroll
            for (int q = 0; q < 4; ++q) {
                w0[q] = sW[(kk + q) * 64 + tc];
                w1[q] = sW[(kk + q) * 64 + tc + 32];
            }
#pragma unroll
            for (int r = 0; r < 6; ++r) {
                float4 av = *(const float4*)(sA + (row0 + r) * 128 + kk);
                a0[r] += av.x * w0[0] + av.y * w0[1] + av.z * w0[2] + av.w * w0[3];
                a1[r] += av.x * w1[0] + av.y * w1[1] + av.z * w1[2] + av.w * w1[3];
            }
        }
#pragma unroll
        for (int r = 0; r < 6; ++r) {
            acc[p * 2 + 0][r] = a0[r];
            acc[p * 2 + 1][r] = a1[r];
        }
    }

    float b0 = bias[tc], b1v = bias[tc + 32], b2v = bias[tc + 64], b3 = bias[tc + 96];
#pragma unroll
    for (int r = 0; r < 6; ++r) {
        int grow = rowBase + row0 + r;
        if (grow < n) {
            size_t base = (size_t)grow * 128;
            Out[base + tc +  0] = fmaxf(acc[0][r] + b0, 0.f);
            Out[base + tc + 32] = fmaxf(acc[1][r] + b1v, 0.f);
            Out[base + tc + 64] = fmaxf(acc[2][r] + b2v, 0.f);
            Out[base + tc + 96] = fmaxf(acc[3][r] + b3, 0.f);
        }
    }
}

extern "C" void kernel_launch(void* const* d_in, const int* in_sizes, int n_in,
                              void* d_out, int out_size, void* d_ws, size_t ws_size,
                              hipStream_t stream) {
    const int n = in_sizes[0] / 128;
    const int e = in_sizes[1] / 2;
    const void* x = d_in[0];
    const int* ei = (const int*)d_in[1];

    char* w = (char*)d_ws;
    size_t o = 0;
    auto alloc = [&](size_t bytes) -> char* {
        char* p = w + o;
        o += (bytes + 255) & ~(size_t)255;
        return p;
    };
    int* flagE = (int*)alloc(4);
    int* flagX = (int*)alloc(4);
    int* cnt   = (int*)alloc((size_t)n * 4);
    int* off   = (int*)alloc((size_t)(n + 1) * 4);
    int* cur   = (int*)alloc((size_t)n * 4);
    float* dinv  = (float*)alloc((size_t)n * 4);
    int* csrc    = (int*)alloc((size_t)e * 4);
    float* cnorm = (float*)alloc((size_t)e * 4);
    float* Wf1 = (float*)alloc(16384 * 4);
    float* Wf2 = (float*)alloc(16384 * 4);
    float* bf1 = (float*)alloc(128 * 4);
    float* bf2 = (float*)alloc(128 * 4);
    __hip_bfloat162* B1 = (__hip_bfloat162*)alloc((size_t)n * 128 * 2);  // bf16 node feats
    (void)ws_size;  // total ~20.7 MB (validated by R4 execution)

    k_detect_e<<<1, 64, 0, stream>>>(ei, flagE);
    k_detect_x<<<1, 64, 0, stream>>>((const unsigned int*)x, flagX);
    k_zero<<<(n + 255) / 256, 256, 0, stream>>>(cnt, n);
    k_convW<<<64, 256, 0, stream>>>(d_in[2], d_in[3], d_in[4], d_in[5], flagX,
                                    Wf1, bf1, Wf2, bf2);
    k_count<<<(e + 255) / 256, 256, 0, stream>>>(ei, flagE, cnt, e, n);
    k_dinv<<<(n + 255) / 256, 256, 0, stream>>>(cnt, dinv, n);
    k_scan64<<<1, 64, 0, stream>>>(cnt, off, cur, n);
    k_fill<<<(e + 255) / 256, 256, 0, stream>>>(ei, flagE, dinv, cur, csrc, cnorm, e, n);

    int gb = (n + 47) / 48;
    int ga = (n + 3) / 4;
    // layer 1: B1 = agg(x); d_out(fp32) = relu(B1 @ W1 + b1)
    k_agg<<<ga, 256, 0, stream>>>(x, flagX, 0, off, csrc, cnorm, dinv, B1, n);
    k_gemm_fused<<<gb, 256, 0, stream>>>((const unsigned short*)B1, Wf1, bf1,
                                         (float*)d_out, n);
    // layer 2: B1 = agg(d_out fp32); d_out(fp32) = relu(B1 @ W2 + b2)
    k_agg<<<ga, 256, 0, stream>>>(d_out, flagX, 1, off, csrc, cnorm, dinv, B1, n);
    k_gemm_fused<<<gb, 256, 0, stream>>>((const unsigned short*)B1, Wf2, bf2,
                                         (float*)d_out, n);
}

// Round 6
// 533.932 us; speedup vs baseline: 1.5719x; 1.5719x over previous
//
#include <hip/hip_runtime.h>
#include <hip/hip_bf16.h>

typedef __hip_bfloat16 bf16h;

__device__ __forceinline__ float bfu2f(unsigned short u) {
    return __uint_as_float(((unsigned int)u) << 16);
}

// ---------------- dtype detectors ----------------
// edge_index: int64 little-endian with values < 50000 => every odd int32 word 0.
__global__ void k_detect_e(const int* __restrict__ ei, int* __restrict__ flag) {
    int lane = threadIdx.x;  // 64 threads
    int v = ei[2 * lane + 1];
    unsigned long long b = __ballot(v == 0);
    if (lane == 0) *flag = (b == ~0ull) ? 1 : 0;
}

// x: packed bf16 pairs -> low 16 bits of each word are a bf16 ~N(0,1): exponent
// field in [0x76,0x82] ~99.8%/lane. fp32 -> those bits are mantissa noise (~5%).
__global__ void k_detect_x(const unsigned int* __restrict__ x, int* __restrict__ flag) {
    int lane = threadIdx.x;  // 64 threads
    unsigned int w = x[lane];
    unsigned int ef = (w >> 7) & 0xFFu;
    unsigned long long b = __ballot(ef >= 0x76u && ef <= 0x82u);
    if (lane == 0) *flag = (__popcll(b) >= 40) ? 1 : 0;
}

__global__ void k_zero(int* __restrict__ p, int n) {
    int i = blockIdx.x * 256 + threadIdx.x;
    if (i < n) p[i] = 0;
}

// convert W1/W2/b1/b2 to fp32 scratch, honoring detected dtype
__global__ void k_convW(const void* __restrict__ W1, const void* __restrict__ b1,
                        const void* __restrict__ W2, const void* __restrict__ b2,
                        const int* __restrict__ xf,
                        float* __restrict__ Wf1, float* __restrict__ bf1,
                        float* __restrict__ Wf2, float* __restrict__ bf2) {
    int i = blockIdx.x * 256 + threadIdx.x;
    bool isb = (*xf != 0);
    if (i < 16384) {
        Wf1[i] = isb ? bfu2f(((const unsigned short*)W1)[i]) : ((const float*)W1)[i];
        Wf2[i] = isb ? bfu2f(((const unsigned short*)W2)[i]) : ((const float*)W2)[i];
    }
    if (i < 128) {
        bf1[i] = isb ? bfu2f(((const unsigned short*)b1)[i]) : ((const float*)b1)[i];
        bf2[i] = isb ? bfu2f(((const unsigned short*)b2)[i]) : ((const float*)b2)[i];
    }
}

// ---------------- CSR build ----------------

__global__ void k_count(const int* __restrict__ ei, const int* __restrict__ flag,
                        int* __restrict__ cnt, int e, int n) {
    int i = blockIdx.x * 256 + threadIdx.x;
    if (i >= e) return;
    int st = (*flag) ? 2 : 1;
    int d = ei[(size_t)e * st + (size_t)i * st];
    if (d >= 0 && d < n) atomicAdd(&cnt[d], 1);
}

__global__ void k_dinv(const int* __restrict__ cnt, float* __restrict__ dinv, int n) {
    int i = blockIdx.x * 256 + threadIdx.x;
    if (i < n) dinv[i] = rsqrtf(fmaxf((float)cnt[i], 0.f) + 1.0f);
}

// single-block scan, 1024 threads x 8 elems/iter = 8192/iter -> 7 iters @ n=50000
__global__ void k_scan(const int* __restrict__ cnt, int* __restrict__ off,
                       int* __restrict__ cur, int n) {
    __shared__ int wsum[16];
    int t = threadIdx.x;
    int lane = t & 63, wid = t >> 6;
    int carry = 0;
    for (int base = 0; base < n; base += 1024 * 8) {
        __syncthreads();  // protect wsum (read at end of previous iteration)
        int i0 = base + t * 8;
        int v[8];
        int s = 0;
#pragma unroll
        for (int j = 0; j < 8; j++) {
            int i = i0 + j;
            v[j] = (i < n) ? cnt[i] : 0;
            s += v[j];
        }
        int incl = s;
#pragma unroll
        for (int d2 = 1; d2 < 64; d2 <<= 1) {
            int u = __shfl_up(incl, d2, 64);
            if (lane >= d2) incl += u;
        }
        if (lane == 63) wsum[wid] = incl;
        __syncthreads();
        if (wid == 0) {
            int ws = (lane < 16) ? wsum[lane] : 0;
#pragma unroll
            for (int d2 = 1; d2 < 16; d2 <<= 1) {
                int u = __shfl_up(ws, d2, 64);
                if (lane >= d2) ws += u;
            }
            if (lane < 16) wsum[lane] = ws;
        }
        __syncthreads();
        int woff = (wid > 0) ? wsum[wid - 1] : 0;
        int excl = carry + woff + (incl - s);
#pragma unroll
        for (int j = 0; j < 8; j++) {
            int i = i0 + j;
            if (i < n) { off[i] = excl; cur[i] = excl; }
            excl += v[j];
        }
        carry += wsum[15];
    }
    if (t == 0) off[n] = carry;
}

__global__ void k_fill(const int* __restrict__ ei, const int* __restrict__ flag,
                       const float* __restrict__ dinv, int* __restrict__ cur,
                       int* __restrict__ csrc, float* __restrict__ cnorm, int e, int n) {
    int i = blockIdx.x * 256 + threadIdx.x;
    if (i >= e) return;
    int st = (*flag) ? 2 : 1;
    int s = ei[(size_t)i * st];
    int d = ei[(size_t)e * st + (size_t)i * st];
    if (s < 0 || s >= n || d < 0 || d >= n) return;
    int pos = atomicAdd(&cur[d], 1);
    csrc[pos] = s;
    cnorm[pos] = dinv[s] * dinv[d];
}

// ---------------- Aggregate (linear): B[v] = sum norm*X[src] + dinv^2*X[v] ----
// One wave/node, 2 elems/lane, fp32 accumulate, bf16x2 store to B.
__global__ __launch_bounds__(256) void k_agg(const void* __restrict__ X,
                                             const int* __restrict__ xflag, int force_f32,
                                             const int* __restrict__ off,
                                             const int* __restrict__ csrc,
                                             const float* __restrict__ cnorm,
                                             const float* __restrict__ dinv,
                                             __hip_bfloat162* __restrict__ outb, int n) {
    int node = blockIdx.x * 4 + (threadIdx.x >> 6);
    if (node >= n) return;
    int lane = threadIdx.x & 63;
    bool isb = (!force_f32) && (*xflag != 0);
    int beg = off[node], end = off[node + 1];
    float ax = 0.f, ay = 0.f;
    if (isb) {
        const unsigned int* Xb = (const unsigned int*)X;  // packed bf16 pair
        for (int j = beg; j < end; ++j) {
            int s = csrc[j];
            if ((unsigned)s >= (unsigned)n) continue;
            float w = cnorm[j];
            unsigned int v = Xb[(size_t)s * 64 + lane];
            ax += w * bfu2f((unsigned short)(v & 0xffffu));
            ay += w * bfu2f((unsigned short)(v >> 16));
        }
        float wd = dinv[node]; wd *= wd;
        unsigned int v = Xb[(size_t)node * 64 + lane];
        ax += wd * bfu2f((unsigned short)(v & 0xffffu));
        ay += wd * bfu2f((unsigned short)(v >> 16));
    } else {
        const float2* Xf = (const float2*)X;
        for (int j = beg; j < end; ++j) {
            int s = csrc[j];
            if ((unsigned)s >= (unsigned)n) continue;
            float w = cnorm[j];
            float2 v = Xf[(size_t)s * 64 + lane];
            ax += w * v.x;
            ay += w * v.y;
        }
        float wd = dinv[node]; wd *= wd;
        float2 v = Xf[(size_t)node * 64 + lane];
        ax += wd * v.x;
        ay += wd * v.y;
    }
    __hip_bfloat162 o;
    o.x = __float2bfloat16(ax);
    o.y = __float2bfloat16(ay);
    outb[(size_t)node * 64 + lane] = o;
}

// ---------------- Fused GEMM: Out_f32 = relu(A_bf16 @ W_f32 + b) ----
// 256 thr, 48 rows/block; thread tile 6 rows x 4 cols; two 64-col passes.
__global__ __launch_bounds__(256) void k_gemm_fused(const unsigned short* __restrict__ A,
                                                    const float* __restrict__ W,
                                                    const float* __restrict__ bias,
                                                    float* __restrict__ Out, int n) {
    __shared__ float sA[48 * 128];
    __shared__ float sW[128 * 64];
    int t = threadIdx.x;
    int rowBase = blockIdx.x * 48;

#pragma unroll
    for (int i = 0; i < 6; ++i) {  // stage A tile bf16 -> fp32
        int idx4 = (t + i * 256) * 4;
        int r = idx4 >> 7, cc = idx4 & 127;
        int grow = rowBase + r;
        float4 f = make_float4(0.f, 0.f, 0.f, 0.f);
        if (grow < n) {
            ushort4 u = *(const ushort4*)(A + (size_t)grow * 128 + cc);
            f.x = bfu2f(u.x); f.y = bfu2f(u.y); f.z = bfu2f(u.z); f.w = bfu2f(u.w);
        }
        *(float4*)(sA + r * 128 + cc) = f;
    }

    int tc = t & 31, tr = t >> 5;
    int row0 = tr * 6;
    float acc[4][6];

    for (int p = 0; p < 2; ++p) {
        __syncthreads();
#pragma unroll
        for (int i = 0; i < 8; ++i) {  // stage W cols [64p,64p+64) verbatim
            int idx4 = (t + i * 256) * 4;
            int k = idx4 >> 6, cc = idx4 & 63;
            *(float4*)(sW + k * 64 + cc) = *(const float4*)(W + k * 128 + 64 * p + cc);
        }
        __syncthreads();

        float a0[6] = {}, a1[6] = {};
        for (int kk = 0; kk < 128; kk += 4) {
            float w0[4], w1[4];
#pragma unroll
            for (int q = 0; q < 4; ++q) {
                w0[q] = sW[(kk + q) * 64 + tc];
                w1[q] = sW[(kk + q) * 64 + tc + 32];
            }
#pragma unroll
            for (int r = 0; r < 6; ++r) {
                float4 av = *(const float4*)(sA + (row0 + r) * 128 + kk);
                a0[r] += av.x * w0[0] + av.y * w0[1] + av.z * w0[2] + av.w * w0[3];
                a1[r] += av.x * w1[0] + av.y * w1[1] + av.z * w1[2] + av.w * w1[3];
            }
        }
#pragma unroll
        for (int r = 0; r < 6; ++r) {
            acc[p * 2 + 0][r] = a0[r];
            acc[p * 2 + 1][r] = a1[r];
        }
    }

    float b0 = bias[tc], b1v = bias[tc + 32], b2v = bias[tc + 64], b3 = bias[tc + 96];
#pragma unroll
    for (int r = 0; r < 6; ++r) {
        int grow = rowBase + row0 + r;
        if (grow < n) {
            size_t base = (size_t)grow * 128;
            Out[base + tc +  0] = fmaxf(acc[0][r] + b0, 0.f);
            Out[base + tc + 32] = fmaxf(acc[1][r] + b1v, 0.f);
            Out[base + tc + 64] = fmaxf(acc[2][r] + b2v, 0.f);
            Out[base + tc + 96] = fmaxf(acc[3][r] + b3, 0.f);
        }
    }
}

extern "C" void kernel_launch(void* const* d_in, const int* in_sizes, int n_in,
                              void* d_out, int out_size, void* d_ws, size_t ws_size,
                              hipStream_t stream) {
    const int n = in_sizes[0] / 128;
    const int e = in_sizes[1] / 2;
    const void* x = d_in[0];
    const int* ei = (const int*)d_in[1];

    char* w = (char*)d_ws;
    size_t o = 0;
    auto alloc = [&](size_t bytes) -> char* {
        char* p = w + o;
        o += (bytes + 255) & ~(size_t)255;
        return p;
    };
    int* flagE = (int*)alloc(4);
    int* flagX = (int*)alloc(4);
    int* cnt   = (int*)alloc((size_t)n * 4);
    int* off   = (int*)alloc((size_t)(n + 1) * 4);
    int* cur   = (int*)alloc((size_t)n * 4);
    float* dinv  = (float*)alloc((size_t)n * 4);
    int* csrc    = (int*)alloc((size_t)e * 4);
    float* cnorm = (float*)alloc((size_t)e * 4);
    float* Wf1 = (float*)alloc(16384 * 4);
    float* Wf2 = (float*)alloc(16384 * 4);
    float* bf1 = (float*)alloc(128 * 4);
    float* bf2 = (float*)alloc(128 * 4);
    __hip_bfloat162* B1 = (__hip_bfloat162*)alloc((size_t)n * 128 * 2);  // bf16 node feats
    (void)ws_size;  // total ~20.7 MB

    k_detect_e<<<1, 64, 0, stream>>>(ei, flagE);
    k_detect_x<<<1, 64, 0, stream>>>((const unsigned int*)x, flagX);
    k_zero<<<(n + 255) / 256, 256, 0, stream>>>(cnt, n);
    k_convW<<<64, 256, 0, stream>>>(d_in[2], d_in[3], d_in[4], d_in[5], flagX,
                                    Wf1, bf1, Wf2, bf2);
    k_count<<<(e + 255) / 256, 256, 0, stream>>>(ei, flagE, cnt, e, n);
    k_dinv<<<(n + 255) / 256, 256, 0, stream>>>(cnt, dinv, n);
    k_scan<<<1, 1024, 0, stream>>>(cnt, off, cur, n);
    k_fill<<<(e + 255) / 256, 256, 0, stream>>>(ei, flagE, dinv, cur, csrc, cnorm, e, n);

    int gb = (n + 47) / 48;
    int ga = (n + 3) / 4;
    // layer 1: B1 = agg(x); d_out(fp32) = relu(B1 @ W1 + b1)
    k_agg<<<ga, 256, 0, stream>>>(x, flagX, 0, off, csrc, cnorm, dinv, B1, n);
    k_gemm_fused<<<gb, 256, 0, stream>>>((const unsigned short*)B1, Wf1, bf1,
                                         (float*)d_out, n);
    // layer 2: B1 = agg(d_out fp32); d_out(fp32) = relu(B1 @ W2 + b2)
    k_agg<<<ga, 256, 0, stream>>>(d_out, flagX, 1, off, csrc, cnorm, dinv, B1, n);
    k_gemm_fused<<<gb, 256, 0, stream>>>((const unsigned short*)B1, Wf2, bf2,
                                         (float*)d_out, n);
}

// Round 7
// 447.544 us; speedup vs baseline: 1.8753x; 1.1930x over previous
//
#include <hip/hip_runtime.h>
#include <hip/hip_bf16.h>

typedef __hip_bfloat16 bf16h;

__device__ __forceinline__ float bfu2f(unsigned int u) {
    return __uint_as_float((u & 0xffffu) << 16);
}
__device__ __forceinline__ float bfhi2f(unsigned int u) {
    return __uint_as_float(u & 0xffff0000u);
}

// ---------------- prep: detect dtypes, zero cnt, convert W/b -> fp32, x -> bf16 table ----
__global__ __launch_bounds__(256) void k_prep(const void* __restrict__ x,
                                              const int* __restrict__ ei,
                                              const void* __restrict__ W1, const void* __restrict__ b1,
                                              const void* __restrict__ W2, const void* __restrict__ b2,
                                              int* __restrict__ flagE, int* __restrict__ cnt,
                                              float* __restrict__ Wf1, float* __restrict__ bfv1,
                                              float* __restrict__ Wf2, float* __restrict__ bfv2,
                                              unsigned int* __restrict__ Xb, int n) {
    int t = threadIdx.x;
    __shared__ int sIsB;
    if (t < 64) {  // wave-0 local bf16-vs-fp32 detection on x (no cross-block dep)
        unsigned int w = ((const unsigned int*)x)[t];
        unsigned int ef = (w >> 7) & 0xFFu;
        unsigned long long b = __ballot(ef >= 0x76u && ef <= 0x82u);
        if (t == 0) sIsB = (__popcll(b) >= 40) ? 1 : 0;
    }
    __syncthreads();
    bool isb = sIsB != 0;

    if (blockIdx.x == 0 && t < 64) {  // edge dtype: int64 => all odd words zero
        int v = ei[2 * t + 1];
        unsigned long long b = __ballot(v == 0);
        if (t == 0) *flagE = (b == ~0ull) ? 1 : 0;
    }

    int gsz = gridDim.x * 256;
    int gid = blockIdx.x * 256 + t;
    for (int i = gid; i < n; i += gsz) cnt[i] = 0;
    for (int i = gid; i < 16384; i += gsz) {
        Wf1[i] = isb ? bfu2f(((const unsigned short*)W1)[i]) : ((const float*)W1)[i];
        Wf2[i] = isb ? bfu2f(((const unsigned short*)W2)[i]) : ((const float*)W2)[i];
    }
    if (gid < 128) {
        bfv1[gid] = isb ? bfu2f(((const unsigned short*)b1)[gid]) : ((const float*)b1)[gid];
        bfv2[gid] = isb ? bfu2f(((const unsigned short*)b2)[gid]) : ((const float*)b2)[gid];
    }
    int total = n * 64;  // packed bf16 pairs
    if (isb) {
        const unsigned int* xs = (const unsigned int*)x;
        for (int i = gid; i < total; i += gsz) Xb[i] = xs[i];
    } else {
        const float2* xf = (const float2*)x;
        for (int i = gid; i < total; i += gsz) {
            float2 v = xf[i];
            __hip_bfloat162 o;
            o.x = __float2bfloat16(v.x);
            o.y = __float2bfloat16(v.y);
            Xb[i] = *(unsigned int*)&o;
        }
    }
}

// ---------------- CSR build ----------------

__global__ void k_count(const int* __restrict__ ei, const int* __restrict__ flag,
                        int* __restrict__ cnt, int e, int n) {
    int i = blockIdx.x * 256 + threadIdx.x;
    if (i >= e) return;
    int st = (*flag) ? 2 : 1;
    int d = ei[(size_t)e * st + (size_t)i * st];
    if (d >= 0 && d < n) atomicAdd(&cnt[d], 1);
}

// single-block scan (1024 thr x 8/iter) + fused dinv
__global__ void k_scan(const int* __restrict__ cnt, int* __restrict__ off,
                       int* __restrict__ cur, float* __restrict__ dinv, int n) {
    __shared__ int wsum[16];
    int t = threadIdx.x;
    int lane = t & 63, wid = t >> 6;
    int carry = 0;
    for (int base = 0; base < n; base += 1024 * 8) {
        __syncthreads();
        int i0 = base + t * 8;
        int v[8];
        int s = 0;
#pragma unroll
        for (int j = 0; j < 8; j++) {
            int i = i0 + j;
            v[j] = (i < n) ? cnt[i] : 0;
            s += v[j];
        }
        int incl = s;
#pragma unroll
        for (int d2 = 1; d2 < 64; d2 <<= 1) {
            int u = __shfl_up(incl, d2, 64);
            if (lane >= d2) incl += u;
        }
        if (lane == 63) wsum[wid] = incl;
        __syncthreads();
        if (wid == 0) {
            int ws = (lane < 16) ? wsum[lane] : 0;
#pragma unroll
            for (int d2 = 1; d2 < 16; d2 <<= 1) {
                int u = __shfl_up(ws, d2, 64);
                if (lane >= d2) ws += u;
            }
            if (lane < 16) wsum[lane] = ws;
        }
        __syncthreads();
        int woff = (wid > 0) ? wsum[wid - 1] : 0;
        int excl = carry + woff + (incl - s);
#pragma unroll
        for (int j = 0; j < 8; j++) {
            int i = i0 + j;
            if (i < n) {
                off[i] = excl;
                cur[i] = excl;
                dinv[i] = rsqrtf((float)v[j] + 1.0f);
            }
            excl += v[j];
        }
        carry += wsum[15];
    }
    if (t == 0) off[n] = carry;
}

__global__ void k_fill(const int* __restrict__ ei, const int* __restrict__ flag,
                       const float* __restrict__ dinv, int* __restrict__ cur,
                       int* __restrict__ csrc, float* __restrict__ cnorm, int e, int n) {
    int i = blockIdx.x * 256 + threadIdx.x;
    if (i >= e) return;
    int st = (*flag) ? 2 : 1;
    int s = ei[(size_t)i * st];
    int d = ei[(size_t)e * st + (size_t)i * st];
    if (s < 0 || s >= n || d < 0 || d >= n) return;
    int pos = atomicAdd(&cur[d], 1);
    csrc[pos] = s;
    cnorm[pos] = dinv[s] * dinv[d];
}

// ---------------- Aggregate: B[v](fp32) = sum norm*Xb[src] + dinv^2*Xb[v] ----
// One wave/node, bf16 table (256 B rows), unroll-4 for 4 gathers in flight.
__global__ __launch_bounds__(256) void k_agg(const unsigned int* __restrict__ Xb,
                                             const int* __restrict__ off,
                                             const int* __restrict__ csrc,
                                             const float* __restrict__ cnorm,
                                             const float* __restrict__ dinv,
                                             float2* __restrict__ outf, int n) {
    int node = blockIdx.x * 4 + (threadIdx.x >> 6);
    if (node >= n) return;
    int lane = threadIdx.x & 63;
    int beg = off[node], end = off[node + 1];
    float ax = 0.f, ay = 0.f;
    int j = beg;
    int nm1 = n - 1;
    for (; j + 4 <= end; j += 4) {
        int s0 = csrc[j], s1 = csrc[j + 1], s2 = csrc[j + 2], s3 = csrc[j + 3];
        float w0 = cnorm[j], w1 = cnorm[j + 1], w2 = cnorm[j + 2], w3 = cnorm[j + 3];
        s0 = min(max(s0, 0), nm1); s1 = min(max(s1, 0), nm1);
        s2 = min(max(s2, 0), nm1); s3 = min(max(s3, 0), nm1);
        unsigned int v0 = Xb[(size_t)s0 * 64 + lane];
        unsigned int v1 = Xb[(size_t)s1 * 64 + lane];
        unsigned int v2 = Xb[(size_t)s2 * 64 + lane];
        unsigned int v3 = Xb[(size_t)s3 * 64 + lane];
        ax += w0 * bfu2f(v0); ay += w0 * bfhi2f(v0);
        ax += w1 * bfu2f(v1); ay += w1 * bfhi2f(v1);
        ax += w2 * bfu2f(v2); ay += w2 * bfhi2f(v2);
        ax += w3 * bfu2f(v3); ay += w3 * bfhi2f(v3);
    }
    for (; j < end; ++j) {
        int s = min(max(csrc[j], 0), nm1);
        float w = cnorm[j];
        unsigned int v = Xb[(size_t)s * 64 + lane];
        ax += w * bfu2f(v); ay += w * bfhi2f(v);
    }
    float wd = dinv[node]; wd *= wd;  // self-loop
    unsigned int v = Xb[(size_t)node * 64 + lane];
    ax += wd * bfu2f(v); ay += wd * bfhi2f(v);
    outf[(size_t)node * 64 + lane] = make_float2(ax, ay);
}

// ---------------- Fused GEMM: out = relu(A_f32 @ W_f32 + b), out fp32 or bf16 ----
// 256 thr, 48 rows/block; thread tile 6 rows x 4 cols; two 64-col passes.
template <bool OUT_BF16>
__global__ __launch_bounds__(256) void k_gemm_fused(const float* __restrict__ A,
                                                    const float* __restrict__ W,
                                                    const float* __restrict__ bias,
                                                    void* __restrict__ out, int n) {
    __shared__ float sA[48 * 128];
    __shared__ float sW[128 * 64];
    int t = threadIdx.x;
    int rowBase = blockIdx.x * 48;

#pragma unroll
    for (int i = 0; i < 6; ++i) {  // stage A tile fp32
        int idx4 = (t + i * 256) * 4;
        int r = idx4 >> 7, cc = idx4 & 127;
        int grow = rowBase + r;
        float4 f = make_float4(0.f, 0.f, 0.f, 0.f);
        if (grow < n) f = *(const float4*)(A + (size_t)grow * 128 + cc);
        *(float4*)(sA + r * 128 + cc) = f;
    }

    int tc = t & 31, tr = t >> 5;
    int row0 = tr * 6;
    float acc[4][6];

    for (int p = 0; p < 2; ++p) {
        __syncthreads();
#pragma unroll
        for (int i = 0; i < 8; ++i) {  // stage W cols [64p,64p+64) verbatim
            int idx4 = (t + i * 256) * 4;
            int k = idx4 >> 6, cc = idx4 & 63;
            *(float4*)(sW + k * 64 + cc) = *(const float4*)(W + k * 128 + 64 * p + cc);
        }
        __syncthreads();

        float a0[6] = {}, a1[6] = {};
        for (int kk = 0; kk < 128; kk += 4) {
            float w0[4], w1[4];
#pragma unroll
            for (int q = 0; q < 4; ++q) {
                w0[q] = sW[(kk + q) * 64 + tc];
                w1[q] = sW[(kk + q) * 64 + tc + 32];
            }
#pragma unroll
            for (int r = 0; r < 6; ++r) {
                float4 av = *(const float4*)(sA + (row0 + r) * 128 + kk);
                a0[r] += av.x * w0[0] + av.y * w0[1] + av.z * w0[2] + av.w * w0[3];
                a1[r] += av.x * w1[0] + av.y * w1[1] + av.z * w1[2] + av.w * w1[3];
            }
        }
#pragma unroll
        for (int r = 0; r < 6; ++r) {
            acc[p * 2 + 0][r] = a0[r];
            acc[p * 2 + 1][r] = a1[r];
        }
    }

    float b0 = bias[tc], b1v = bias[tc + 32], b2v = bias[tc + 64], b3 = bias[tc + 96];
#pragma unroll
    for (int r = 0; r < 6; ++r) {
        int grow = rowBase + row0 + r;
        if (grow < n) {
            size_t base = (size_t)grow * 128;
            float o0 = fmaxf(acc[0][r] + b0, 0.f);
            float o1 = fmaxf(acc[1][r] + b1v, 0.f);
            float o2 = fmaxf(acc[2][r] + b2v, 0.f);
            float o3 = fmaxf(acc[3][r] + b3, 0.f);
            if constexpr (OUT_BF16) {
                bf16h* O = (bf16h*)out;
                O[base + tc +  0] = __float2bfloat16(o0);
                O[base + tc + 32] = __float2bfloat16(o1);
                O[base + tc + 64] = __float2bfloat16(o2);
                O[base + tc + 96] = __float2bfloat16(o3);
            } else {
                float* O = (float*)out;
                O[base + tc +  0] = o0;
                O[base + tc + 32] = o1;
                O[base + tc + 64] = o2;
                O[base + tc + 96] = o3;
            }
        }
    }
}

extern "C" void kernel_launch(void* const* d_in, const int* in_sizes, int n_in,
                              void* d_out, int out_size, void* d_ws, size_t ws_size,
                              hipStream_t stream) {
    const int n = in_sizes[0] / 128;
    const int e = in_sizes[1] / 2;
    const void* x = d_in[0];
    const int* ei = (const int*)d_in[1];

    char* w = (char*)d_ws;
    size_t o = 0;
    auto alloc = [&](size_t bytes) -> char* {
        char* p = w + o;
        o += (bytes + 255) & ~(size_t)255;
        return p;
    };
    int* flagE = (int*)alloc(4);
    int* cnt   = (int*)alloc((size_t)n * 4);
    int* off   = (int*)alloc((size_t)(n + 1) * 4);
    int* cur   = (int*)alloc((size_t)n * 4);
    float* dinv  = (float*)alloc((size_t)n * 4);
    int* csrc    = (int*)alloc((size_t)e * 4);
    float* cnorm = (float*)alloc((size_t)e * 4);
    float* Wf1 = (float*)alloc(16384 * 4);
    float* Wf2 = (float*)alloc(16384 * 4);
    float* bf1 = (float*)alloc(128 * 4);
    float* bf2 = (float*)alloc(128 * 4);
    unsigned int* Xb = (unsigned int*)alloc((size_t)n * 64 * 4);  // bf16 gather table (reused L2)
    float* B1 = (float*)alloc((size_t)n * 128 * 4);               // fp32 agg output
    (void)ws_size;  // ~46 MB (<= 58.4 MB validated in R1-R3)

    k_prep<<<1024, 256, 0, stream>>>(x, ei, d_in[2], d_in[3], d_in[4], d_in[5],
                                     flagE, cnt, Wf1, bf1, Wf2, bf2, Xb, n);
    k_count<<<(e + 255) / 256, 256, 0, stream>>>(ei, flagE, cnt, e, n);
    k_scan<<<1, 1024, 0, stream>>>(cnt, off, cur, dinv, n);
    k_fill<<<(e + 255) / 256, 256, 0, stream>>>(ei, flagE, dinv, cur, csrc, cnorm, e, n);

    int gb = (n + 47) / 48;
    int ga = (n + 3) / 4;
    // layer 1: B1 = agg(Xb); Xb <- bf16(relu(B1 @ W1 + b1))
    k_agg<<<ga, 256, 0, stream>>>(Xb, off, csrc, cnorm, dinv, (float2*)B1, n);
    k_gemm_fused<true><<<gb, 256, 0, stream>>>(B1, Wf1, bf1, Xb, n);
    // layer 2: B1 = agg(Xb); d_out(fp32) = relu(B1 @ W2 + b2)
    k_agg<<<ga, 256, 0, stream>>>(Xb, off, csrc, cnorm, dinv, (float2*)B1, n);
    k_gemm_fused<false><<<gb, 256, 0, stream>>>(B1, Wf2, bf2, d_out, n);
}

// Round 8
// 373.931 us; speedup vs baseline: 2.2445x; 1.1969x over previous
//
#include <hip/hip_runtime.h>
#include <hip/hip_bf16.h>

typedef __hip_bfloat16 bf16h;

__device__ __forceinline__ float bfu2f(unsigned int u) {
    return __uint_as_float((u & 0xffffu) << 16);
}
__device__ __forceinline__ float bfhi2f(unsigned int u) {
    return __uint_as_float(u & 0xffff0000u);
}

// ---------------- prep: detect dtypes, zero cnt, convert W/b -> fp32, x -> bf16 table ----
__global__ __launch_bounds__(256) void k_prep(const void* __restrict__ x,
                                              const int* __restrict__ ei,
                                              const void* __restrict__ W1, const void* __restrict__ b1,
                                              const void* __restrict__ W2, const void* __restrict__ b2,
                                              int* __restrict__ flagE, int* __restrict__ cnt,
                                              float* __restrict__ Wf1, float* __restrict__ bfv1,
                                              float* __restrict__ Wf2, float* __restrict__ bfv2,
                                              unsigned int* __restrict__ Xb, int n) {
    int t = threadIdx.x;
    __shared__ int sIsB;
    if (t < 64) {  // per-block local bf16-vs-fp32 detection on x (no cross-block dep)
        unsigned int w = ((const unsigned int*)x)[t];
        unsigned int ef = (w >> 7) & 0xFFu;
        unsigned long long b = __ballot(ef >= 0x76u && ef <= 0x82u);
        if (t == 0) sIsB = (__popcll(b) >= 40) ? 1 : 0;
    }
    __syncthreads();
    bool isb = sIsB != 0;

    if (blockIdx.x == 0 && t < 64) {  // edge dtype: int64 => all odd words zero
        int v = ei[2 * t + 1];
        unsigned long long b = __ballot(v == 0);
        if (t == 0) *flagE = (b == ~0ull) ? 1 : 0;
    }

    int gsz = gridDim.x * 256;
    int gid = blockIdx.x * 256 + t;
    for (int i = gid; i < n; i += gsz) cnt[i] = 0;
    for (int i = gid; i < 16384; i += gsz) {
        Wf1[i] = isb ? bfu2f(((const unsigned short*)W1)[i]) : ((const float*)W1)[i];
        Wf2[i] = isb ? bfu2f(((const unsigned short*)W2)[i]) : ((const float*)W2)[i];
    }
    if (gid < 128) {
        bfv1[gid] = isb ? bfu2f(((const unsigned short*)b1)[gid]) : ((const float*)b1)[gid];
        bfv2[gid] = isb ? bfu2f(((const unsigned short*)b2)[gid]) : ((const float*)b2)[gid];
    }
    int total = n * 64;  // packed bf16 pairs
    if (isb) {
        const unsigned int* xs = (const unsigned int*)x;
        for (int i = gid; i < total; i += gsz) Xb[i] = xs[i];
    } else {
        const float2* xf = (const float2*)x;
        for (int i = gid; i < total; i += gsz) {
            float2 v = xf[i];
            __hip_bfloat162 o;
            o.x = __float2bfloat16(v.x);
            o.y = __float2bfloat16(v.y);
            Xb[i] = *(unsigned int*)&o;
        }
    }
}

// ---------------- CSR build ----------------

__global__ void k_count(const int* __restrict__ ei, const int* __restrict__ flag,
                        int* __restrict__ cnt, int e, int n) {
    int i = blockIdx.x * 256 + threadIdx.x;
    if (i >= e) return;
    int st = (*flag) ? 2 : 1;
    int d = ei[(size_t)e * st + (size_t)i * st];
    if (d >= 0 && d < n) atomicAdd(&cnt[d], 1);
}

// scan phase 1: per-block (256-elem) partial sums
__global__ __launch_bounds__(256) void k_bsum(const int* __restrict__ cnt,
                                              int* __restrict__ part, int n) {
    int t = threadIdx.x;
    int i = blockIdx.x * 256 + t;
    int v = (i < n) ? cnt[i] : 0;
#pragma unroll
    for (int m = 1; m < 64; m <<= 1) v += __shfl_xor(v, m, 64);
    __shared__ int ws[4];
    if ((t & 63) == 0) ws[t >> 6] = v;
    __syncthreads();
    if (t == 0) part[blockIdx.x] = ws[0] + ws[1] + ws[2] + ws[3];
}

// scan phase 2: single-wave exclusive scan over nb partials
__global__ void k_pscan(const int* __restrict__ part, int* __restrict__ ppre, int nb) {
    int lane = threadIdx.x;  // 64 threads
    int carry = 0;
    for (int base = 0; base < nb; base += 64) {
        int i = base + lane;
        int v = (i < nb) ? part[i] : 0;
        int incl = v;
#pragma unroll
        for (int d = 1; d < 64; d <<= 1) {
            int u = __shfl_up(incl, d, 64);
            if (lane >= d) incl += u;
        }
        if (i < nb) ppre[i] = carry + incl - v;
        carry += __shfl(incl, 63, 64);
    }
}

// scan phase 3: block-local scan + prefix, write off/cur/dinv (+off[n])
__global__ __launch_bounds__(256) void k_bscan(const int* __restrict__ cnt,
                                               const int* __restrict__ ppre,
                                               int* __restrict__ off, int* __restrict__ cur,
                                               float* __restrict__ dinv, int n) {
    int t = threadIdx.x;
    int lane = t & 63, wid = t >> 6;
    int i = blockIdx.x * 256 + t;
    int v = (i < n) ? cnt[i] : 0;
    int incl = v;
#pragma unroll
    for (int d = 1; d < 64; d <<= 1) {
        int u = __shfl_up(incl, d, 64);
        if (lane >= d) incl += u;
    }
    __shared__ int ws[4], wo[4];
    if (lane == 63) ws[wid] = incl;
    __syncthreads();
    if (t == 0) {
        int s = 0;
#pragma unroll
        for (int k = 0; k < 4; ++k) { wo[k] = s; s += ws[k]; }
    }
    __syncthreads();
    int excl = ppre[blockIdx.x] + wo[wid] + incl - v;
    if (i < n) {
        off[i] = excl;
        cur[i] = excl;
        dinv[i] = rsqrtf((float)v + 1.0f);
        if (i == n - 1) off[n] = excl + v;
    }
}

__global__ void k_fill(const int* __restrict__ ei, const int* __restrict__ flag,
                       const float* __restrict__ dinv, int* __restrict__ cur,
                       int* __restrict__ csrc, float* __restrict__ cnorm, int e, int n) {
    int i = blockIdx.x * 256 + threadIdx.x;
    if (i >= e) return;
    int st = (*flag) ? 2 : 1;
    int s = ei[(size_t)i * st];
    int d = ei[(size_t)e * st + (size_t)i * st];
    if (s < 0 || s >= n || d < 0 || d >= n) return;
    int pos = atomicAdd(&cur[d], 1);
    csrc[pos] = s;
    cnorm[pos] = dinv[s] * dinv[d];
}

// ---------------- Aggregate: B[v](fp32) = sum norm*Xb[src] + dinv^2*Xb[v] ----
// One wave/node. Half-wave edge split: lanes 0-31 even edges, 32-63 odd edges;
// each lane loads uint2 (4 bf16 feats); unroll x4 => 8 row-gathers in flight/wave.
__global__ __launch_bounds__(256) void k_agg(const unsigned int* __restrict__ Xb,
                                             const int* __restrict__ off,
                                             const int* __restrict__ csrc,
                                             const float* __restrict__ cnorm,
                                             const float* __restrict__ dinv,
                                             float4* __restrict__ outf, int n) {
    int node = blockIdx.x * 4 + (threadIdx.x >> 6);
    if (node >= n) return;
    int lane = threadIdx.x & 63;
    int hw = lane >> 5;   // half-wave id
    int hl = lane & 31;   // half-lane
    int col = hl * 2;     // uint column (uint2 load -> 4 bf16 features)
    int beg = off[node], end = off[node + 1];
    int nm1 = n - 1;
    float4 acc = make_float4(0.f, 0.f, 0.f, 0.f);
    for (int j = beg; j < end; j += 8) {
#pragma unroll
        for (int k = 0; k < 4; ++k) {
            int jj = j + 2 * k + hw;
            bool ok = jj < end;
            int s = ok ? csrc[jj] : node;
            float w = ok ? cnorm[jj] : 0.f;
            s = min(max(s, 0), nm1);
            uint2 v = *(const uint2*)(Xb + (size_t)s * 64 + col);
            acc.x += w * bfu2f(v.x);
            acc.y += w * bfhi2f(v.x);
            acc.z += w * bfu2f(v.y);
            acc.w += w * bfhi2f(v.y);
        }
    }
    // combine the two half-wave partials
    acc.x += __shfl_xor(acc.x, 32, 64);
    acc.y += __shfl_xor(acc.y, 32, 64);
    acc.z += __shfl_xor(acc.z, 32, 64);
    acc.w += __shfl_xor(acc.w, 32, 64);
    if (hw == 0) {
        float wd = dinv[node];
        wd *= wd;  // self-loop
        uint2 v = *(const uint2*)(Xb + (size_t)node * 64 + col);
        acc.x += wd * bfu2f(v.x);
        acc.y += wd * bfhi2f(v.x);
        acc.z += wd * bfu2f(v.y);
        acc.w += wd * bfhi2f(v.y);
        outf[(size_t)node * 32 + hl] = acc;
    }
}

// ---------------- Fused GEMM: out = relu(A_f32 @ W_f32 + b), out fp32 or bf16 ----
template <bool OUT_BF16>
__global__ __launch_bounds__(256) void k_gemm_fused(const float* __restrict__ A,
                                                    const float* __restrict__ W,
                                                    const float* __restrict__ bias,
                                                    void* __restrict__ out, int n) {
    __shared__ float sA[48 * 128];
    __shared__ float sW[128 * 64];
    int t = threadIdx.x;
    int rowBase = blockIdx.x * 48;

#pragma unroll
    for (int i = 0; i < 6; ++i) {  // stage A tile fp32
        int idx4 = (t + i * 256) * 4;
        int r = idx4 >> 7, cc = idx4 & 127;
        int grow = rowBase + r;
        float4 f = make_float4(0.f, 0.f, 0.f, 0.f);
        if (grow < n) f = *(const float4*)(A + (size_t)grow * 128 + cc);
        *(float4*)(sA + r * 128 + cc) = f;
    }

    int tc = t & 31, tr = t >> 5;
    int row0 = tr * 6;
    float acc[4][6];

    for (int p = 0; p < 2; ++p) {
        __syncthreads();
#pragma unroll
        for (int i = 0; i < 8; ++i) {  // stage W cols [64p,64p+64) verbatim
            int idx4 = (t + i * 256) * 4;
            int k = idx4 >> 6, cc = idx4 & 63;
            *(float4*)(sW + k * 64 + cc) = *(const float4*)(W + k * 128 + 64 * p + cc);
        }
        __syncthreads();

        float a0[6] = {}, a1[6] = {};
        for (int kk = 0; kk < 128; kk += 4) {
            float w0[4], w1[4];
#pragma unroll
            for (int q = 0; q < 4; ++q) {
                w0[q] = sW[(kk + q) * 64 + tc];
                w1[q] = sW[(kk + q) * 64 + tc + 32];
            }
#pragma unroll
            for (int r = 0; r < 6; ++r) {
                float4 av = *(const float4*)(sA + (row0 + r) * 128 + kk);
                a0[r] += av.x * w0[0] + av.y * w0[1] + av.z * w0[2] + av.w * w0[3];
                a1[r] += av.x * w1[0] + av.y * w1[1] + av.z * w1[2] + av.w * w1[3];
            }
        }
#pragma unroll
        for (int r = 0; r < 6; ++r) {
            acc[p * 2 + 0][r] = a0[r];
            acc[p * 2 + 1][r] = a1[r];
        }
    }

    float b0 = bias[tc], b1v = bias[tc + 32], b2v = bias[tc + 64], b3 = bias[tc + 96];
#pragma unroll
    for (int r = 0; r < 6; ++r) {
        int grow = rowBase + row0 + r;
        if (grow < n) {
            size_t base = (size_t)grow * 128;
            float o0 = fmaxf(acc[0][r] + b0, 0.f);
            float o1 = fmaxf(acc[1][r] + b1v, 0.f);
            float o2 = fmaxf(acc[2][r] + b2v, 0.f);
            float o3 = fmaxf(acc[3][r] + b3, 0.f);
            if constexpr (OUT_BF16) {
                bf16h* O = (bf16h*)out;
                O[base + tc +  0] = __float2bfloat16(o0);
                O[base + tc + 32] = __float2bfloat16(o1);
                O[base + tc + 64] = __float2bfloat16(o2);
                O[base + tc + 96] = __float2bfloat16(o3);
            } else {
                float* O = (float*)out;
                O[base + tc +  0] = o0;
                O[base + tc + 32] = o1;
                O[base + tc + 64] = o2;
                O[base + tc + 96] = o3;
            }
        }
    }
}

extern "C" void kernel_launch(void* const* d_in, const int* in_sizes, int n_in,
                              void* d_out, int out_size, void* d_ws, size_t ws_size,
                              hipStream_t stream) {
    const int n = in_sizes[0] / 128;
    const int e = in_sizes[1] / 2;
    const void* x = d_in[0];
    const int* ei = (const int*)d_in[1];

    char* w = (char*)d_ws;
    size_t o = 0;
    auto alloc = [&](size_t bytes) -> char* {
        char* p = w + o;
        o += (bytes + 255) & ~(size_t)255;
        return p;
    };
    const int nb = (n + 255) / 256;  // scan blocks
    int* flagE = (int*)alloc(4);
    int* cnt   = (int*)alloc((size_t)n * 4);
    int* off   = (int*)alloc((size_t)(n + 1) * 4);
    int* cur   = (int*)alloc((size_t)n * 4);
    float* dinv  = (float*)alloc((size_t)n * 4);
    int* part  = (int*)alloc((size_t)nb * 4);
    int* ppre  = (int*)alloc((size_t)nb * 4);
    int* csrc    = (int*)alloc((size_t)e * 4);
    float* cnorm = (float*)alloc((size_t)e * 4);
    float* Wf1 = (float*)alloc(16384 * 4);
    float* Wf2 = (float*)alloc(16384 * 4);
    float* bf1 = (float*)alloc(128 * 4);
    float* bf2 = (float*)alloc(128 * 4);
    unsigned int* Xb = (unsigned int*)alloc((size_t)n * 64 * 4);  // bf16 gather table
    float* B1 = (float*)alloc((size_t)n * 128 * 4);               // fp32 agg output
    (void)ws_size;  // ~46 MB

    k_prep<<<1024, 256, 0, stream>>>(x, ei, d_in[2], d_in[3], d_in[4], d_in[5],
                                     flagE, cnt, Wf1, bf1, Wf2, bf2, Xb, n);
    k_count<<<(e + 255) / 256, 256, 0, stream>>>(ei, flagE, cnt, e, n);
    k_bsum<<<nb, 256, 0, stream>>>(cnt, part, n);
    k_pscan<<<1, 64, 0, stream>>>(part, ppre, nb);
    k_bscan<<<nb, 256, 0, stream>>>(cnt, ppre, off, cur, dinv, n);
    k_fill<<<(e + 255) / 256, 256, 0, stream>>>(ei, flagE, dinv, cur, csrc, cnorm, e, n);

    int gb = (n + 47) / 48;
    int ga = (n + 3) / 4;
    // layer 1: B1 = agg(Xb); Xb <- bf16(relu(B1 @ W1 + b1))
    k_agg<<<ga, 256, 0, stream>>>(Xb, off, csrc, cnorm, dinv, (float4*)B1, n);
    k_gemm_fused<true><<<gb, 256, 0, stream>>>(B1, Wf1, bf1, Xb, n);
    // layer 2: B1 = agg(Xb); d_out(fp32) = relu(B1 @ W2 + b2)
    k_agg<<<ga, 256, 0, stream>>>(Xb, off, csrc, cnorm, dinv, (float4*)B1, n);
    k_gemm_fused<false><<<gb, 256, 0, stream>>>(B1, Wf2, bf2, d_out, n);
}

// Round 9
// 303.558 us; speedup vs baseline: 2.7648x; 1.2318x over previous
//
#include <hip/hip_runtime.h>
#include <hip/hip_bf16.h>

typedef __hip_bfloat16 bf16h;
typedef short short8 __attribute__((ext_vector_type(8)));
typedef float floatx4 __attribute__((ext_vector_type(4)));

__device__ __forceinline__ float bfu2f(unsigned int u) {
    return __uint_as_float((u & 0xffffu) << 16);
}
__device__ __forceinline__ float bfhi2f(unsigned int u) {
    return __uint_as_float(u & 0xffff0000u);
}
__device__ __forceinline__ unsigned short f2bfu(float f) {
    bf16h b = __float2bfloat16(f);  // RNE
    return *(unsigned short*)&b;
}

// ---------------- prep: detect dtypes, zero cnt, W -> MFMA bf16 hi/lo fragments,
//                  bias -> fp32, x -> bf16 gather table ----
// W fragment layout (B-operand, 16x16x32): idx = ((c*4+kk)*64 + lane)*8 + j
//   holds W[k = kk*32 + (lane>>4)*8 + j][n = c*16 + (lane&15)]
__global__ __launch_bounds__(256) void k_prep(const void* __restrict__ x,
                                              const int* __restrict__ ei,
                                              const void* __restrict__ W1, const void* __restrict__ b1,
                                              const void* __restrict__ W2, const void* __restrict__ b2,
                                              int* __restrict__ flagE, int* __restrict__ cnt,
                                              unsigned short* __restrict__ W1h, unsigned short* __restrict__ W1l,
                                              unsigned short* __restrict__ W2h, unsigned short* __restrict__ W2l,
                                              float* __restrict__ bfv1, float* __restrict__ bfv2,
                                              unsigned int* __restrict__ Xb, int n) {
    int t = threadIdx.x;
    __shared__ int sIsB;
    if (t < 64) {  // per-block local bf16-vs-fp32 detection on x (no cross-block dep)
        unsigned int w = ((const unsigned int*)x)[t];
        unsigned int ef = (w >> 7) & 0xFFu;
        unsigned long long b = __ballot(ef >= 0x76u && ef <= 0x82u);
        if (t == 0) sIsB = (__popcll(b) >= 40) ? 1 : 0;
    }
    __syncthreads();
    bool isb = sIsB != 0;

    if (blockIdx.x == 0 && t < 64) {  // edge dtype: int64 => all odd words zero
        int v = ei[2 * t + 1];
        unsigned long long b = __ballot(v == 0);
        if (t == 0) *flagE = (b == ~0ull) ? 1 : 0;
    }

    int gsz = gridDim.x * 256;
    int gid = blockIdx.x * 256 + t;
    for (int i = gid; i < n; i += gsz) cnt[i] = 0;
    for (int i = gid; i < 16384; i += gsz) {
        // decompose fragment index
        int c  = i >> 11;
        int kk = (i >> 9) & 3;
        int ln = (i >> 3) & 63;
        int j  = i & 7;
        int k    = kk * 32 + (ln >> 4) * 8 + j;
        int ncol = c * 16 + (ln & 15);
        int src  = k * 128 + ncol;
        float v1 = isb ? bfu2f(((const unsigned short*)W1)[src]) : ((const float*)W1)[src];
        float v2 = isb ? bfu2f(((const unsigned short*)W2)[src]) : ((const float*)W2)[src];
        unsigned short h1 = f2bfu(v1), h2 = f2bfu(v2);
        W1h[i] = h1; W1l[i] = f2bfu(v1 - bfu2f(h1));
        W2h[i] = h2; W2l[i] = f2bfu(v2 - bfu2f(h2));
    }
    if (gid < 128) {
        bfv1[gid] = isb ? bfu2f(((const unsigned short*)b1)[gid]) : ((const float*)b1)[gid];
        bfv2[gid] = isb ? bfu2f(((const unsigned short*)b2)[gid]) : ((const float*)b2)[gid];
    }
    int total = n * 64;  // packed bf16 pairs
    if (isb) {
        const unsigned int* xs = (const unsigned int*)x;
        for (int i = gid; i < total; i += gsz) Xb[i] = xs[i];
    } else {
        const float2* xf = (const float2*)x;
        for (int i = gid; i < total; i += gsz) {
            float2 v = xf[i];
            __hip_bfloat162 o;
            o.x = __float2bfloat16(v.x);
            o.y = __float2bfloat16(v.y);
            Xb[i] = *(unsigned int*)&o;
        }
    }
}

// ---------------- CSR build ----------------

__global__ void k_count(const int* __restrict__ ei, const int* __restrict__ flag,
                        int* __restrict__ cnt, int e, int n) {
    int i = blockIdx.x * 256 + threadIdx.x;
    if (i >= e) return;
    int st = (*flag) ? 2 : 1;
    int d = ei[(size_t)e * st + (size_t)i * st];
    if (d >= 0 && d < n) atomicAdd(&cnt[d], 1);
}

// scan phase 1: per-block (256-elem) partial sums
__global__ __launch_bounds__(256) void k_bsum(const int* __restrict__ cnt,
                                              int* __restrict__ part, int n) {
    int t = threadIdx.x;
    int i = blockIdx.x * 256 + t;
    int v = (i < n) ? cnt[i] : 0;
#pragma unroll
    for (int m = 1; m < 64; m <<= 1) v += __shfl_xor(v, m, 64);
    __shared__ int ws[4];
    if ((t & 63) == 0) ws[t >> 6] = v;
    __syncthreads();
    if (t == 0) part[blockIdx.x] = ws[0] + ws[1] + ws[2] + ws[3];
}

// scan phase 2: single-wave exclusive scan over nb partials
__global__ void k_pscan(const int* __restrict__ part, int* __restrict__ ppre, int nb) {
    int lane = threadIdx.x;  // 64 threads
    int carry = 0;
    for (int base = 0; base < nb; base += 64) {
        int i = base + lane;
        int v = (i < nb) ? part[i] : 0;
        int incl = v;
#pragma unroll
        for (int d = 1; d < 64; d <<= 1) {
            int u = __shfl_up(incl, d, 64);
            if (lane >= d) incl += u;
        }
        if (i < nb) ppre[i] = carry + incl - v;
        carry += __shfl(incl, 63, 64);
    }
}

// scan phase 3: block-local scan + prefix, write off/cur/dinv (+off[n])
__global__ __launch_bounds__(256) void k_bscan(const int* __restrict__ cnt,
                                               const int* __restrict__ ppre,
                                               int* __restrict__ off, int* __restrict__ cur,
                                               float* __restrict__ dinv, int n) {
    int t = threadIdx.x;
    int lane = t & 63, wid = t >> 6;
    int i = blockIdx.x * 256 + t;
    int v = (i < n) ? cnt[i] : 0;
    int incl = v;
#pragma unroll
    for (int d = 1; d < 64; d <<= 1) {
        int u = __shfl_up(incl, d, 64);
        if (lane >= d) incl += u;
    }
    __shared__ int ws[4], wo[4];
    if (lane == 63) ws[wid] = incl;
    __syncthreads();
    if (t == 0) {
        int s = 0;
#pragma unroll
        for (int k = 0; k < 4; ++k) { wo[k] = s; s += ws[k]; }
    }
    __syncthreads();
    int excl = ppre[blockIdx.x] + wo[wid] + incl - v;
    if (i < n) {
        off[i] = excl;
        cur[i] = excl;
        dinv[i] = rsqrtf((float)v + 1.0f);
        if (i == n - 1) off[n] = excl + v;
    }
}

__global__ void k_fill(const int* __restrict__ ei, const int* __restrict__ flag,
                       const float* __restrict__ dinv, int* __restrict__ cur,
                       int* __restrict__ csrc, float* __restrict__ cnorm, int e, int n) {
    int i = blockIdx.x * 256 + threadIdx.x;
    if (i >= e) return;
    int st = (*flag) ? 2 : 1;
    int s = ei[(size_t)i * st];
    int d = ei[(size_t)e * st + (size_t)i * st];
    if (s < 0 || s >= n || d < 0 || d >= n) return;
    int pos = atomicAdd(&cur[d], 1);
    csrc[pos] = s;
    cnorm[pos] = dinv[s] * dinv[d];
}

// ---------------- Aggregate: B[v](fp32) = sum norm*Xb[src] + dinv^2*Xb[v] ----
// One wave/node; half-wave edge split; uint2/lane; 8 row-gathers in flight.
__global__ __launch_bounds__(256) void k_agg(const unsigned int* __restrict__ Xb,
                                             const int* __restrict__ off,
                                             const int* __restrict__ csrc,
                                             const float* __restrict__ cnorm,
                                             const float* __restrict__ dinv,
                                             float4* __restrict__ outf, int n) {
    int node = blockIdx.x * 4 + (threadIdx.x >> 6);
    if (node >= n) return;
    int lane = threadIdx.x & 63;
    int hw = lane >> 5;   // half-wave id
    int hl = lane & 31;   // half-lane
    int col = hl * 2;     // uint column (uint2 load -> 4 bf16 features)
    int beg = off[node], end = off[node + 1];
    int nm1 = n - 1;
    float4 acc = make_float4(0.f, 0.f, 0.f, 0.f);
    for (int j = beg; j < end; j += 8) {
#pragma unroll
        for (int k = 0; k < 4; ++k) {
            int jj = j + 2 * k + hw;
            bool ok = jj < end;
            int s = ok ? csrc[jj] : node;
            float w = ok ? cnorm[jj] : 0.f;
            s = min(max(s, 0), nm1);
            uint2 v = *(const uint2*)(Xb + (size_t)s * 64 + col);
            acc.x += w * bfu2f(v.x);
            acc.y += w * bfhi2f(v.x);
            acc.z += w * bfu2f(v.y);
            acc.w += w * bfhi2f(v.y);
        }
    }
    acc.x += __shfl_xor(acc.x, 32, 64);
    acc.y += __shfl_xor(acc.y, 32, 64);
    acc.z += __shfl_xor(acc.z, 32, 64);
    acc.w += __shfl_xor(acc.w, 32, 64);
    if (hw == 0) {
        float wd = dinv[node];
        wd *= wd;  // self-loop
        uint2 v = *(const uint2*)(Xb + (size_t)node * 64 + col);
        acc.x += wd * bfu2f(v.x);
        acc.y += wd * bfhi2f(v.x);
        acc.z += wd * bfu2f(v.y);
        acc.w += wd * bfhi2f(v.y);
        outf[(size_t)node * 32 + hl] = acc;
    }
}

// ---------------- MFMA GEMM: out = relu(A_f32 @ W + b), split-precision bf16 ----
// A fp32 split per element into bf16 hi+lo; W pre-split in fragment layout.
// D = Ah*Wh + Al*Wh + Ah*Wl  (missing terms ~2^-16 relative).
// Wave: 16 rows x 128 cols; block = 4 waves = 64 rows. No LDS.
template <bool OUT_BF16>
__global__ __launch_bounds__(256) void k_gemm_mfma(const float* __restrict__ A,
                                                   const unsigned short* __restrict__ Wh,
                                                   const unsigned short* __restrict__ Wl,
                                                   const float* __restrict__ bias,
                                                   void* __restrict__ out, int n) {
    int t = threadIdx.x;
    int wv = t >> 6, lane = t & 63;
    int quad = lane >> 4, l16 = lane & 15;
    int rowBase = blockIdx.x * 64 + wv * 16;
    int m = rowBase + l16;                    // row this lane loads A for
    size_t arow = (size_t)min(m, n - 1) * 128;
    bool mok = m < n;

    floatx4 acc[8];
#pragma unroll
    for (int c = 0; c < 8; ++c) acc[c] = (floatx4){0.f, 0.f, 0.f, 0.f};

#pragma unroll
    for (int kk = 0; kk < 4; ++kk) {
        const float* ap = A + arow + kk * 32 + quad * 8;
        float4 a0 = mok ? *(const float4*)(ap) : make_float4(0.f, 0.f, 0.f, 0.f);
        float4 a1 = mok ? *(const float4*)(ap + 4) : make_float4(0.f, 0.f, 0.f, 0.f);
        float av[8] = {a0.x, a0.y, a0.z, a0.w, a1.x, a1.y, a1.z, a1.w};
        short8 ah, al;
#pragma unroll
        for (int j = 0; j < 8; ++j) {
            unsigned short h = f2bfu(av[j]);
            ah[j] = (short)h;
            al[j] = (short)f2bfu(av[j] - bfu2f(h));
        }
#pragma unroll
        for (int c = 0; c < 8; ++c) {
            int fo = ((c * 4 + kk) * 64 + lane) * 8;
            short8 bh = *(const short8*)(Wh + fo);
            short8 bl = *(const short8*)(Wl + fo);
            acc[c] = __builtin_amdgcn_mfma_f32_16x16x32_bf16(ah, bh, acc[c], 0, 0, 0);
            acc[c] = __builtin_amdgcn_mfma_f32_16x16x32_bf16(al, bh, acc[c], 0, 0, 0);
            acc[c] = __builtin_amdgcn_mfma_f32_16x16x32_bf16(ah, bl, acc[c], 0, 0, 0);
        }
    }

    // epilogue: C/D layout col = lane&15, row = quad*4 + reg  [m89-verified]
#pragma unroll
    for (int c = 0; c < 8; ++c) {
        int ncol = c * 16 + l16;
        float bv = bias[ncol];
#pragma unroll
        for (int r = 0; r < 4; ++r) {
            int row = rowBase + quad * 4 + r;
            if (row < n) {
                float o = fmaxf(acc[c][r] + bv, 0.f);
                if constexpr (OUT_BF16) {
                    ((unsigned short*)out)[(size_t)row * 128 + ncol] = f2bfu(o);
                } else {
                    ((float*)out)[(size_t)row * 128 + ncol] = o;
                }
            }
        }
    }
}

extern "C" void kernel_launch(void* const* d_in, const int* in_sizes, int n_in,
                              void* d_out, int out_size, void* d_ws, size_t ws_size,
                              hipStream_t stream) {
    const int n = in_sizes[0] / 128;
    const int e = in_sizes[1] / 2;
    const void* x = d_in[0];
    const int* ei = (const int*)d_in[1];

    char* w = (char*)d_ws;
    size_t o = 0;
    auto alloc = [&](size_t bytes) -> char* {
        char* p = w + o;
        o += (bytes + 255) & ~(size_t)255;
        return p;
    };
    const int nb = (n + 255) / 256;  // scan blocks
    int* flagE = (int*)alloc(4);
    int* cnt   = (int*)alloc((size_t)n * 4);
    int* off   = (int*)alloc((size_t)(n + 1) * 4);
    int* cur   = (int*)alloc((size_t)n * 4);
    float* dinv  = (float*)alloc((size_t)n * 4);
    int* part  = (int*)alloc((size_t)nb * 4);
    int* ppre  = (int*)alloc((size_t)nb * 4);
    int* csrc    = (int*)alloc((size_t)e * 4);
    float* cnorm = (float*)alloc((size_t)e * 4);
    unsigned short* W1h = (unsigned short*)alloc(16384 * 2);
    unsigned short* W1l = (unsigned short*)alloc(16384 * 2);
    unsigned short* W2h = (unsigned short*)alloc(16384 * 2);
    unsigned short* W2l = (unsigned short*)alloc(16384 * 2);
    float* bf1 = (float*)alloc(128 * 4);
    float* bf2 = (float*)alloc(128 * 4);
    unsigned int* Xb = (unsigned int*)alloc((size_t)n * 64 * 4);  // bf16 gather table
    float* B1 = (float*)alloc((size_t)n * 128 * 4);               // fp32 agg output
    (void)ws_size;  // ~45 MB

    k_prep<<<1024, 256, 0, stream>>>(x, ei, d_in[2], d_in[3], d_in[4], d_in[5],
                                     flagE, cnt, W1h, W1l, W2h, W2l, bf1, bf2, Xb, n);
    k_count<<<(e + 255) / 256, 256, 0, stream>>>(ei, flagE, cnt, e, n);
    k_bsum<<<nb, 256, 0, stream>>>(cnt, part, n);
    k_pscan<<<1, 64, 0, stream>>>(part, ppre, nb);
    k_bscan<<<nb, 256, 0, stream>>>(cnt, ppre, off, cur, dinv, n);
    k_fill<<<(e + 255) / 256, 256, 0, stream>>>(ei, flagE, dinv, cur, csrc, cnorm, e, n);

    int gm = (n + 63) / 64;
    int ga = (n + 3) / 4;
    // layer 1: B1 = agg(Xb); Xb <- bf16(relu(B1 @ W1 + b1))
    k_agg<<<ga, 256, 0, stream>>>(Xb, off, csrc, cnorm, dinv, (float4*)B1, n);
    k_gemm_mfma<true><<<gm, 256, 0, stream>>>(B1, W1h, W1l, bf1, Xb, n);
    // layer 2: B1 = agg(Xb); d_out(fp32) = relu(B1 @ W2 + b2)
    k_agg<<<ga, 256, 0, stream>>>(Xb, off, csrc, cnorm, dinv, (float4*)B1, n);
    k_gemm_mfma<false><<<gm, 256, 0, stream>>>(B1, W2h, W2l, bf2, d_out, n);
}

// Round 10
// 292.652 us; speedup vs baseline: 2.8678x; 1.0373x over previous
//
#include <hip/hip_runtime.h>
#include <hip/hip_bf16.h>

typedef __hip_bfloat16 bf16h;
typedef short short8 __attribute__((ext_vector_type(8)));
typedef float floatx4 __attribute__((ext_vector_type(4)));

__device__ __forceinline__ float bfu2f(unsigned int u) {
    return __uint_as_float((u & 0xffffu) << 16);
}
__device__ __forceinline__ float bfhi2f(unsigned int u) {
    return __uint_as_float(u & 0xffff0000u);
}
__device__ __forceinline__ unsigned short f2bfu(float f) {
    bf16h b = __float2bfloat16(f);  // RNE
    return *(unsigned short*)&b;
}

// ---------------- prep: detect dtypes, zero cnt, W -> MFMA bf16 hi/lo fragments,
//                  bias -> fp32, x -> bf16 gather table ----
// W fragment layout (B-operand, 16x16x32): idx = ((c*4+kk)*64 + lane)*8 + j
//   holds W[k = kk*32 + (lane>>4)*8 + j][n = c*16 + (lane&15)]
__global__ __launch_bounds__(256) void k_prep(const void* __restrict__ x,
                                              const int* __restrict__ ei,
                                              const void* __restrict__ W1, const void* __restrict__ b1,
                                              const void* __restrict__ W2, const void* __restrict__ b2,
                                              int* __restrict__ flagE, int* __restrict__ cnt,
                                              unsigned short* __restrict__ W1h, unsigned short* __restrict__ W1l,
                                              unsigned short* __restrict__ W2h, unsigned short* __restrict__ W2l,
                                              float* __restrict__ bfv1, float* __restrict__ bfv2,
                                              unsigned int* __restrict__ Xb, int n) {
    int t = threadIdx.x;
    __shared__ int sIsB;
    if (t < 64) {  // per-block local bf16-vs-fp32 detection on x
        unsigned int w = ((const unsigned int*)x)[t];
        unsigned int ef = (w >> 7) & 0xFFu;
        unsigned long long b = __ballot(ef >= 0x76u && ef <= 0x82u);
        if (t == 0) sIsB = (__popcll(b) >= 40) ? 1 : 0;
    }
    __syncthreads();
    bool isb = sIsB != 0;

    if (blockIdx.x == 0 && t < 64) {  // edge dtype: int64 => all odd words zero
        int v = ei[2 * t + 1];
        unsigned long long b = __ballot(v == 0);
        if (t == 0) *flagE = (b == ~0ull) ? 1 : 0;
    }

    int gsz = gridDim.x * 256;
    int gid = blockIdx.x * 256 + t;
    for (int i = gid; i < n; i += gsz) cnt[i] = 0;
    for (int i = gid; i < 16384; i += gsz) {
        int c  = i >> 11;
        int kk = (i >> 9) & 3;
        int ln = (i >> 3) & 63;
        int j  = i & 7;
        int k    = kk * 32 + (ln >> 4) * 8 + j;
        int ncol = c * 16 + (ln & 15);
        int src  = k * 128 + ncol;
        float v1 = isb ? bfu2f(((const unsigned short*)W1)[src]) : ((const float*)W1)[src];
        float v2 = isb ? bfu2f(((const unsigned short*)W2)[src]) : ((const float*)W2)[src];
        unsigned short h1 = f2bfu(v1), h2 = f2bfu(v2);
        W1h[i] = h1; W1l[i] = f2bfu(v1 - bfu2f(h1));
        W2h[i] = h2; W2l[i] = f2bfu(v2 - bfu2f(h2));
    }
    if (gid < 128) {
        bfv1[gid] = isb ? bfu2f(((const unsigned short*)b1)[gid]) : ((const float*)b1)[gid];
        bfv2[gid] = isb ? bfu2f(((const unsigned short*)b2)[gid]) : ((const float*)b2)[gid];
    }
    int total = n * 64;  // packed bf16 pairs
    if (isb) {
        const unsigned int* xs = (const unsigned int*)x;
        for (int i = gid; i < total; i += gsz) Xb[i] = xs[i];
    } else {
        const float2* xf = (const float2*)x;
        for (int i = gid; i < total; i += gsz) {
            float2 v = xf[i];
            __hip_bfloat162 o;
            o.x = __float2bfloat16(v.x);
            o.y = __float2bfloat16(v.y);
            Xb[i] = *(unsigned int*)&o;
        }
    }
}

// ---------------- CSR build ----------------

// 4 edges/thread: batched independent loads then atomics
__global__ __launch_bounds__(256) void k_count(const int* __restrict__ ei,
                                               const int* __restrict__ flag,
                                               int* __restrict__ cnt, int e, int n) {
    int base = (blockIdx.x * 256 + threadIdx.x) * 4;
    int st = (*flag) ? 2 : 1;
    int d[4];
#pragma unroll
    for (int k = 0; k < 4; ++k) {
        int i = base + k;
        d[k] = (i < e) ? ei[(size_t)e * st + (size_t)i * st] : -1;
    }
#pragma unroll
    for (int k = 0; k < 4; ++k)
        if (d[k] >= 0 && d[k] < n) atomicAdd(&cnt[d[k]], 1);
}

// scan phase 1: per-block (256-elem) partial sums
__global__ __launch_bounds__(256) void k_bsum(const int* __restrict__ cnt,
                                              int* __restrict__ part, int n) {
    int t = threadIdx.x;
    int i = blockIdx.x * 256 + t;
    int v = (i < n) ? cnt[i] : 0;
#pragma unroll
    for (int m = 1; m < 64; m <<= 1) v += __shfl_xor(v, m, 64);
    __shared__ int ws[4];
    if ((t & 63) == 0) ws[t >> 6] = v;
    __syncthreads();
    if (t == 0) part[blockIdx.x] = ws[0] + ws[1] + ws[2] + ws[3];
}

// scan phase 2: single-wave exclusive scan over nb partials
__global__ void k_pscan(const int* __restrict__ part, int* __restrict__ ppre, int nb) {
    int lane = threadIdx.x;  // 64 threads
    int carry = 0;
    for (int base = 0; base < nb; base += 64) {
        int i = base + lane;
        int v = (i < nb) ? part[i] : 0;
        int incl = v;
#pragma unroll
        for (int d = 1; d < 64; d <<= 1) {
            int u = __shfl_up(incl, d, 64);
            if (lane >= d) incl += u;
        }
        if (i < nb) ppre[i] = carry + incl - v;
        carry += __shfl(incl, 63, 64);
    }
}

// scan phase 3: block-local scan + prefix, write off/cur/dinv (+off[n])
__global__ __launch_bounds__(256) void k_bscan(const int* __restrict__ cnt,
                                               const int* __restrict__ ppre,
                                               int* __restrict__ off, int* __restrict__ cur,
                                               float* __restrict__ dinv, int n) {
    int t = threadIdx.x;
    int lane = t & 63, wid = t >> 6;
    int i = blockIdx.x * 256 + t;
    int v = (i < n) ? cnt[i] : 0;
    int incl = v;
#pragma unroll
    for (int d = 1; d < 64; d <<= 1) {
        int u = __shfl_up(incl, d, 64);
        if (lane >= d) incl += u;
    }
    __shared__ int ws[4], wo[4];
    if (lane == 63) ws[wid] = incl;
    __syncthreads();
    if (t == 0) {
        int s = 0;
#pragma unroll
        for (int k = 0; k < 4; ++k) { wo[k] = s; s += ws[k]; }
    }
    __syncthreads();
    int excl = ppre[blockIdx.x] + wo[wid] + incl - v;
    if (i < n) {
        off[i] = excl;
        cur[i] = excl;
        dinv[i] = rsqrtf((float)v + 1.0f);
        if (i == n - 1) off[n] = excl + v;
    }
}

// 4 edges/thread; packed (src, norm) single 8B store per edge
__global__ __launch_bounds__(256) void k_fill(const int* __restrict__ ei,
                                              const int* __restrict__ flag,
                                              const float* __restrict__ dinv,
                                              int* __restrict__ cur,
                                              int2* __restrict__ edge, int e, int n) {
    int base = (blockIdx.x * 256 + threadIdx.x) * 4;
    int st = (*flag) ? 2 : 1;
    int s[4], d[4];
#pragma unroll
    for (int k = 0; k < 4; ++k) {
        int i = base + k;
        bool ok = i < e;
        s[k] = ok ? ei[(size_t)i * st] : -1;
        d[k] = ok ? ei[(size_t)e * st + (size_t)i * st] : -1;
    }
    float ds[4], dd[4];
#pragma unroll
    for (int k = 0; k < 4; ++k) {
        int sc = min(max(s[k], 0), n - 1), dc = min(max(d[k], 0), n - 1);
        ds[k] = dinv[sc];
        dd[k] = dinv[dc];
    }
#pragma unroll
    for (int k = 0; k < 4; ++k) {
        if (s[k] >= 0 && s[k] < n && d[k] >= 0 && d[k] < n) {
            int pos = atomicAdd(&cur[d[k]], 1);
            edge[pos] = make_int2(s[k], __float_as_int(ds[k] * dd[k]));
        }
    }
}

// ---------------- Aggregate: B[v](fp32) = sum norm*Xb[src] + dinv^2*Xb[v] ----
// One wave/node; quarter-wave groups: 4 groups x 16 lanes, each group loads a
// full 256B row via uint4/lane; unroll 4 => 16 rows in flight per wave.
__global__ __launch_bounds__(256) void k_agg(const unsigned int* __restrict__ Xb,
                                             const int* __restrict__ off,
                                             const int2* __restrict__ edge,
                                             const float* __restrict__ dinv,
                                             float* __restrict__ outf, int n) {
    int node = blockIdx.x * 4 + (threadIdx.x >> 6);
    if (node >= n) return;
    int lane = threadIdx.x & 63;
    int g = lane >> 4;    // group 0..3
    int l = lane & 15;    // lane in group
    int col = l * 4;      // uint index: 16 lanes x uint4 = full 128-feature row
    int beg = off[node], end = off[node + 1];
    int nm1 = n - 1;
    float acc[8] = {0.f, 0.f, 0.f, 0.f, 0.f, 0.f, 0.f, 0.f};
    for (int j = beg; j < end; j += 16) {
#pragma unroll
        for (int k = 0; k < 4; ++k) {
            int jj = j + k * 4 + g;
            bool ok = jj < end;
            int2 er = ok ? edge[jj] : make_int2(node, 0);
            float w = ok ? __int_as_float(er.y) : 0.f;
            int s = min(max(er.x, 0), nm1);
            uint4 v = *(const uint4*)(Xb + (size_t)s * 64 + col);
            acc[0] += w * bfu2f(v.x);  acc[1] += w * bfhi2f(v.x);
            acc[2] += w * bfu2f(v.y);  acc[3] += w * bfhi2f(v.y);
            acc[4] += w * bfu2f(v.z);  acc[5] += w * bfhi2f(v.z);
            acc[6] += w * bfu2f(v.w);  acc[7] += w * bfhi2f(v.w);
        }
    }
#pragma unroll
    for (int i = 0; i < 8; ++i) {
        acc[i] += __shfl_xor(acc[i], 16, 64);
        acc[i] += __shfl_xor(acc[i], 32, 64);
    }
    if (g == 0) {
        float wd = dinv[node];
        wd *= wd;  // self-loop
        uint4 v = *(const uint4*)(Xb + (size_t)node * 64 + col);
        acc[0] += wd * bfu2f(v.x);  acc[1] += wd * bfhi2f(v.x);
        acc[2] += wd * bfu2f(v.y);  acc[3] += wd * bfhi2f(v.y);
        acc[4] += wd * bfu2f(v.z);  acc[5] += wd * bfhi2f(v.z);
        acc[6] += wd * bfu2f(v.w);  acc[7] += wd * bfhi2f(v.w);
        float* po = outf + (size_t)node * 128 + l * 8;
        *(float4*)(po)     = make_float4(acc[0], acc[1], acc[2], acc[3]);
        *(float4*)(po + 4) = make_float4(acc[4], acc[5], acc[6], acc[7]);
    }
}

// ---------------- MFMA GEMM: out = relu(A_f32 @ W + b), split-precision bf16 ----
// D = Ah*Wh + Al*Wh + Ah*Wl. Wave: 16 rows x 128 cols; block = 64 rows. No LDS.
template <bool OUT_BF16>
__global__ __launch_bounds__(256) void k_gemm_mfma(const float* __restrict__ A,
                                                   const unsigned short* __restrict__ Wh,
                                                   const unsigned short* __restrict__ Wl,
                                                   const float* __restrict__ bias,
                                                   void* __restrict__ out, int n) {
    int t = threadIdx.x;
    int wv = t >> 6, lane = t & 63;
    int quad = lane >> 4, l16 = lane & 15;
    int rowBase = blockIdx.x * 64 + wv * 16;
    int m = rowBase + l16;
    size_t arow = (size_t)min(m, n - 1) * 128;
    bool mok = m < n;

    floatx4 acc[8];
#pragma unroll
    for (int c = 0; c < 8; ++c) acc[c] = (floatx4){0.f, 0.f, 0.f, 0.f};

#pragma unroll
    for (int kk = 0; kk < 4; ++kk) {
        const float* ap = A + arow + kk * 32 + quad * 8;
        float4 a0 = mok ? *(const float4*)(ap) : make_float4(0.f, 0.f, 0.f, 0.f);
        float4 a1 = mok ? *(const float4*)(ap + 4) : make_float4(0.f, 0.f, 0.f, 0.f);
        float av[8] = {a0.x, a0.y, a0.z, a0.w, a1.x, a1.y, a1.z, a1.w};
        short8 ah, al;
#pragma unroll
        for (int j = 0; j < 8; ++j) {
            unsigned short h = f2bfu(av[j]);
            ah[j] = (short)h;
            al[j] = (short)f2bfu(av[j] - bfu2f(h));
        }
#pragma unroll
        for (int c = 0; c < 8; ++c) {
            int fo = ((c * 4 + kk) * 64 + lane) * 8;
            short8 bh = *(const short8*)(Wh + fo);
            short8 bl = *(const short8*)(Wl + fo);
            acc[c] = __builtin_amdgcn_mfma_f32_16x16x32_bf16(ah, bh, acc[c], 0, 0, 0);
            acc[c] = __builtin_amdgcn_mfma_f32_16x16x32_bf16(al, bh, acc[c], 0, 0, 0);
            acc[c] = __builtin_amdgcn_mfma_f32_16x16x32_bf16(ah, bl, acc[c], 0, 0, 0);
        }
    }

    // epilogue: C/D layout col = lane&15, row = quad*4 + reg  [m89-verified]
#pragma unroll
    for (int c = 0; c < 8; ++c) {
        int ncol = c * 16 + l16;
        float bv = bias[ncol];
#pragma unroll
        for (int r = 0; r < 4; ++r) {
            int row = rowBase + quad * 4 + r;
            if (row < n) {
                float o = fmaxf(acc[c][r] + bv, 0.f);
                if constexpr (OUT_BF16) {
                    ((unsigned short*)out)[(size_t)row * 128 + ncol] = f2bfu(o);
                } else {
                    ((float*)out)[(size_t)row * 128 + ncol] = o;
                }
            }
        }
    }
}

extern "C" void kernel_launch(void* const* d_in, const int* in_sizes, int n_in,
                              void* d_out, int out_size, void* d_ws, size_t ws_size,
                              hipStream_t stream) {
    const int n = in_sizes[0] / 128;
    const int e = in_sizes[1] / 2;
    const void* x = d_in[0];
    const int* ei = (const int*)d_in[1];

    char* w = (char*)d_ws;
    size_t o = 0;
    auto alloc = [&](size_t bytes) -> char* {
        char* p = w + o;
        o += (bytes + 255) & ~(size_t)255;
        return p;
    };
    const int nb = (n + 255) / 256;  // scan blocks
    int* flagE = (int*)alloc(4);
    int* cnt   = (int*)alloc((size_t)n * 4);
    int* off   = (int*)alloc((size_t)(n + 1) * 4);
    int* cur   = (int*)alloc((size_t)n * 4);
    float* dinv  = (float*)alloc((size_t)n * 4);
    int* part  = (int*)alloc((size_t)nb * 4);
    int* ppre  = (int*)alloc((size_t)nb * 4);
    int2* edge = (int2*)alloc((size_t)e * 8);  // packed (src, norm)
    unsigned short* W1h = (unsigned short*)alloc(16384 * 2);
    unsigned short* W1l = (unsigned short*)alloc(16384 * 2);
    unsigned short* W2h = (unsigned short*)alloc(16384 * 2);
    unsigned short* W2l = (unsigned short*)alloc(16384 * 2);
    float* bf1 = (float*)alloc(128 * 4);
    float* bf2 = (float*)alloc(128 * 4);
    unsigned int* Xb = (unsigned int*)alloc((size_t)n * 64 * 4);  // bf16 gather table
    float* B1 = (float*)alloc((size_t)n * 128 * 4);               // fp32 agg output
    (void)ws_size;  // ~46 MB

    k_prep<<<1024, 256, 0, stream>>>(x, ei, d_in[2], d_in[3], d_in[4], d_in[5],
                                     flagE, cnt, W1h, W1l, W2h, W2l, bf1, bf2, Xb, n);
    int ec4 = (e + 1023) / 1024;
    k_count<<<ec4, 256, 0, stream>>>(ei, flagE, cnt, e, n);
    k_bsum<<<nb, 256, 0, stream>>>(cnt, part, n);
    k_pscan<<<1, 64, 0, stream>>>(part, ppre, nb);
    k_bscan<<<nb, 256, 0, stream>>>(cnt, ppre, off, cur, dinv, n);
    k_fill<<<ec4, 256, 0, stream>>>(ei, flagE, dinv, cur, edge, e, n);

    int gm = (n + 63) / 64;
    int ga = (n + 3) / 4;
    // layer 1: B1 = agg(Xb); Xb <- bf16(relu(B1 @ W1 + b1))
    k_agg<<<ga, 256, 0, stream>>>(Xb, off, edge, dinv, B1, n);
    k_gemm_mfma<true><<<gm, 256, 0, stream>>>(B1, W1h, W1l, bf1, Xb, n);
    // layer 2: B1 = agg(Xb); d_out(fp32) = relu(B1 @ W2 + b2)
    k_agg<<<ga, 256, 0, stream>>>(Xb, off, edge, dinv, B1, n);
    k_gemm_mfma<false><<<gm, 256, 0, stream>>>(B1, W2h, W2l, bf2, d_out, n);
}